// Round 4
// baseline (156.387 us; speedup 1.0000x reference)
//
#include <hip/hip_runtime.h>

// Problem: B=2, C=256, F*H*W=N=4096, heads=4, dim_head=64, inner=256
#define BATCH 2
#define CCH   256
#define NSEQ  4096
#define NH    4
#define DH    64
#define INNER 256

typedef __attribute__((ext_vector_type(8))) __bf16 bf16x8;
typedef __attribute__((ext_vector_type(4))) float f32x4;
typedef __attribute__((ext_vector_type(8))) unsigned short u16x8;
typedef __attribute__((ext_vector_type(4))) unsigned short u16x4;

// async global->LDS, 16B per lane; LDS dest = wave-uniform base + lane*16
#define GLD16(gsrc, ldst)                                                     \
  __builtin_amdgcn_global_load_lds(                                           \
      (const __attribute__((address_space(1))) unsigned int*)(const void*)(gsrc), \
      (__attribute__((address_space(3))) unsigned int*)(void*)(ldst), 16, 0, 0)

// round-half-up bf16 (inputs finite; <=0.5ulp bias vs RNE, irrelevant here)
static __device__ __forceinline__ unsigned short f2bfr(float f) {
  union { float f; unsigned u; } v; v.f = f;
  return (unsigned short)((v.u + 0x8000u) >> 16);
}
// pack two floats -> bf16 pair (low = f0) via v_perm_b32: 3 VALU ops
static __device__ __forceinline__ unsigned pack2(float f0, float f1) {
  union { float f; unsigned u; } a, b; a.f = f0; b.f = f1;
  return __builtin_amdgcn_perm(b.u + 0x8000u, a.u + 0x8000u, 0x07060302u);
}
// 1-op pack: v_cvt_pk_bf16_f32 (RNE; fine at bf16 tolerance)
static __device__ __forceinline__ unsigned cvtpk(float lo, float hi) {
  unsigned r;
  asm("v_cvt_pk_bf16_f32 %0, %1, %2" : "=v"(r) : "v"(lo), "v"(hi));
  return r;
}
static __device__ __forceinline__ float bf2f(unsigned short u) {
  union { unsigned u; float f; } v; v.u = ((unsigned)u) << 16;
  return v.f;
}
static __device__ __forceinline__ bf16x8 ldb(const unsigned short* p) {
  return *(const bf16x8*)p;
}
static __device__ __forceinline__ f32x4 mm(bf16x8 a, bf16x8 b, f32x4 c) {
  return __builtin_amdgcn_mfma_f32_16x16x32_bf16(a, b, c, 0, 0, 0);
}
// raw v_exp_f32: inputs bounded to |x| <= ~11.6, no denormal fixup needed
static __device__ __forceinline__ float ex2(float x) {
  return __builtin_amdgcn_exp2f(x);
}

// ------ Kernel 1: LN -> xn [b][n][c] bf16  (+ fused fp32->bf16 weight cvt) --
__global__ __launch_bounds__(256) void k_lncvt(const float* __restrict__ x,
                                               const float* __restrict__ gamma,
                                               unsigned short* __restrict__ xn,
                                               const float* __restrict__ wq,
                                               const float* __restrict__ wo,
                                               unsigned short* __restrict__ wqb,
                                               unsigned short* __restrict__ wob) {
  int blk = blockIdx.x;
  if (blk >= 256) {                       // weight convert: 256 blocks
    int t = (blk - 256) * 256 + threadIdx.x;
    int e = t * 4;
    if (e < 768 * 256) {
      float4 v = *(const float4*)(wq + e);
      u16x4 pk = { f2bfr(v.x), f2bfr(v.y), f2bfr(v.z), f2bfr(v.w) };
      *(u16x4*)(wqb + e) = pk;
    } else {
      int e2 = e - 768 * 256;
      float4 v = *(const float4*)(wo + e2);
      u16x4 pk = { f2bfr(v.x), f2bfr(v.y), f2bfr(v.z), f2bfr(v.w) };
      *(u16x4*)(wob + e2) = pk;
    }
    return;
  }
  int b  = blk >> 7;
  int n0 = (blk & 127) * 32;
  int t  = threadIdx.x;
  int nl = t & 31;
  int cg = t >> 5;                 // channel group 0..7 (32 channels each)
  int n  = n0 + nl;
  const float* xp = x + ((size_t)(b * CCH + cg * 32)) * NSEQ + n;
  float vals[32];
  float s = 0.f, s2 = 0.f;
#pragma unroll
  for (int j = 0; j < 32; j++) {
    float v = xp[(size_t)j * NSEQ];
    vals[j] = v; s += v; s2 += v * v;
  }
  __shared__ float rs[8][32], rs2[8][32];
  rs[cg][nl] = s; rs2[cg][nl] = s2;
  __syncthreads();
  float S = 0.f, S2 = 0.f;
#pragma unroll
  for (int g = 0; g < 8; g++) { S += rs[g][nl]; S2 += rs2[g][nl]; }
  float mean = S * (1.f / 256.f);
  float var  = S2 * (1.f / 256.f) - mean * mean;
  float rstd = rsqrtf(var + 1e-5f);
  unsigned short* dst = xn + ((size_t)b * NSEQ + n) * CCH + cg * 32;
#pragma unroll
  for (int j0 = 0; j0 < 32; j0 += 8) {
    u16x8 pk;
#pragma unroll
    for (int j = 0; j < 8; j++)
      pk[j] = f2bfr((vals[j0 + j] - mean) * rstd * gamma[cg * 32 + j0 + j]);
    *(u16x8*)(dst + j0) = pk;
  }
}

// --- Kernel 2: QKV GEMM + fused l2norm, full-K staging (1 main barrier) ----
// oi 0..3: q head oi -> qt (scaled 8*log2e); 4..7: k -> ktb; 8..11: v -> qkv.
__global__ __launch_bounds__(256) void k_qkv(const unsigned short* __restrict__ wqb,
                                             const unsigned short* __restrict__ xn,
                                             unsigned short* __restrict__ qkv,
                                             unsigned short* __restrict__ qt,
                                             unsigned short* __restrict__ ktb) {
  int n0 = blockIdx.x * 64;
  int oi = blockIdx.y;
  int o0 = oi * 64;
  int b  = blockIdx.z;
  __shared__ unsigned short Al[64 * 256];   // [o][k] swizzled, 32 KB
  __shared__ unsigned short Bl[64 * 256];   // [n][k] swizzled, 32 KB
  int t = threadIdx.x;
  int lane = t & 63, w = t >> 6;
  int c = lane & 15, quad = lane >> 4;
  int wm = w >> 1, wn = w & 1;
  f32x4 acc[2][2] = {};
  int lr2 = lane >> 5;                      // row within pair (0..1)
  int lch = lane & 31;                      // phys chunk (32 chunks/row)
  const unsigned short* apg = wqb + (size_t)o0 * CCH;
  const unsigned short* bpg = xn + ((size_t)b * NSEQ + n0) * CCH;
#pragma unroll
  for (int q = 0; q < 8; q++) {
    int r = w * 16 + q * 2 + lr2;
    int srcoff = r * CCH + ((lch ^ (r & 7)) * 8);
    GLD16(apg + srcoff, Al + (size_t)(w * 16 + q * 2) * 256);
    GLD16(bpg + srcoff, Bl + (size_t)(w * 16 + q * 2) * 256);
  }
  __syncthreads();
#pragma unroll
  for (int ks = 0; ks < 8; ks++) {
    int ra0 = wm * 32 + c, ra1 = ra0 + 16;
    int rb0 = wn * 32 + c, rb1 = rb0 + 16;
    bf16x8 a0 = ldb(&Al[ra0 * 256 + (((ks * 4 + quad) ^ (ra0 & 7)) * 8)]);
    bf16x8 a1 = ldb(&Al[ra1 * 256 + (((ks * 4 + quad) ^ (ra1 & 7)) * 8)]);
    bf16x8 b0 = ldb(&Bl[rb0 * 256 + (((ks * 4 + quad) ^ (rb0 & 7)) * 8)]);
    bf16x8 b1 = ldb(&Bl[rb1 * 256 + (((ks * 4 + quad) ^ (rb1 & 7)) * 8)]);
    acc[0][0] = mm(a0, b0, acc[0][0]);
    acc[0][1] = mm(a0, b1, acc[0][1]);
    acc[1][0] = mm(a1, b0, acc[1][0]);
    acc[1][1] = mm(a1, b1, acc[1][1]);
  }
  if (oi < 8) {
    // per-n sum of squares: this wave covers d in [wm*32, wm*32+32)
    float* sq = (float*)Al;                 // reuse Al after final reads
    float s0 = 0.f, s1 = 0.f;
#pragma unroll
    for (int i = 0; i < 2; i++)
#pragma unroll
      for (int rr = 0; rr < 4; rr++) {
        s0 += acc[i][0][rr] * acc[i][0][rr];
        s1 += acc[i][1][rr] * acc[i][1][rr];
      }
    s0 += __shfl_xor(s0, 16); s0 += __shfl_xor(s0, 32);
    s1 += __shfl_xor(s1, 16); s1 += __shfl_xor(s1, 32);
    __syncthreads();
    if (quad == 0) {
      sq[wm * 64 + wn * 32 + c]      = s0;
      sq[wm * 64 + wn * 32 + 16 + c] = s1;
    }
    __syncthreads();
    float r0 = rsqrtf(sq[wn * 32 + c]      + sq[64 + wn * 32 + c]      + 1e-12f);
    float r1 = rsqrtf(sq[wn * 32 + 16 + c] + sq[64 + wn * 32 + 16 + c] + 1e-12f);
    if (oi < 4) { r0 *= 11.541560327111707f; r1 *= 11.541560327111707f; } // 8*log2e
    int h = oi & 3;
    unsigned short* base = (oi < 4 ? qt : ktb) + ((size_t)(b * NH + h) * NSEQ) * DH;
#pragma unroll
    for (int i = 0; i < 2; i++)
#pragma unroll
      for (int j = 0; j < 2; j++) {
        float rsc = j ? r1 : r0;
        int n = n0 + wn * 32 + j * 16 + c;
        int d = wm * 32 + i * 16 + quad * 4;
        uint2 pk = { pack2(acc[i][j][0] * rsc, acc[i][j][1] * rsc),
                     pack2(acc[i][j][2] * rsc, acc[i][j][3] * rsc) };
        *(uint2*)(base + (size_t)n * DH + d) = pk;
      }
  } else {
#pragma unroll
    for (int i = 0; i < 2; i++)
#pragma unroll
      for (int j = 0; j < 2; j++)
#pragma unroll
        for (int rr = 0; rr < 4; rr++) {
          int o = o0 + wm * 32 + i * 16 + quad * 4 + rr;
          int n = n0 + wn * 32 + j * 16 + c;
          qkv[((size_t)b * 768 + o) * NSEQ + n] = f2bfr(acc[i][j][rr]);
        }
  }
}

// ------ Kernel 3: flash attention, Q-tile 128, LDS = V only (16 KB) --------
// K comes straight from global into per-lane A-fragments (L2-served); the
// QK MFMAs use row-permuted K (A-row a holds K row sigma_t(a) =
// (a>>2)*8+(a&3)+(t&1)*4+(t>>1)*32) so each lane's S outputs land exactly at
// its PV A-fragment positions: P = cvt_pk(exp2(z)) entirely in registers —
// no P LDS roundtrip, no K LDS staging, ONE barrier per KV-tile (V dbuf).
// LDS traffic/wave-iter drops 26KB -> 10KB (was ~70% of the 85 B/cy ds
// ceiling). Max-free softmax (|sim|<=8 folded as 8*log2e into q), split-KV.
__global__ __launch_bounds__(256, 4) void k_attn(
    const unsigned short* __restrict__ qt,
    const unsigned short* __restrict__ ktb,
    const unsigned short* __restrict__ qkv,
    unsigned short* __restrict__ opart,
    float* __restrict__ lpart,
    int S, int kvlen) {
  int i0 = blockIdx.x * 128;
  int h  = blockIdx.y;
  int bz = blockIdx.z;
  int b  = bz / S, s = bz % S;
  __shared__ unsigned short Vl[2][64 * 64];  // [d][j] swizzled, 2x8 KB
  int t = threadIdx.x;
  int lane = t & 63, w = t >> 6;
  int c = lane & 15, quad = lane >> 4;

  const unsigned short* qbase = qt  + ((size_t)(b * NH + h) * NSEQ) * DH;
  const unsigned short* kbase = ktb + ((size_t)(b * NH + h) * NSEQ) * DH;
  const unsigned short* vbase = qkv + ((size_t)b * 768 + 512 + h * 64) * NSEQ;

  // Q fragments straight from global (one-time, L2-served)
  int rlo = w * 32 + c, rhi = rlo + 16;     // local q-rows of this lane
  const unsigned short* qlo = qbase + (size_t)(i0 + rlo) * DH + quad * 8;
  const unsigned short* qhi = qlo + 16 * DH;
  bf16x8 qlo0 = ldb(qlo), qlo1 = ldb(qlo + 32);
  bf16x8 qhi0 = ldb(qhi), qhi1 = ldb(qhi + 32);

  u16x8 onesu;
#pragma unroll
  for (int j = 0; j < 8; j++) onesu[j] = 0x3F80;               // bf16 1.0
  bf16x8 ones = *(bf16x8*)&onesu;

  f32x4 acclo[4] = {}, acchi[4] = {};
  f32x4 accllo = {}, acclhi = {};

  // V staging: lane covers d-row w*16 + {0,8} + (lane>>3), phys chunk lane&7
  int slr = lane >> 3, slc = lane & 7;
  int ssw = (slc ^ slr) * 8;                // swizzled source elem offset
  const unsigned short* vp = vbase + (size_t)(w * 16 + slr) * NSEQ + s * kvlen + ssw;
  int sw0 = (quad ^ (c & 7)) * 8;           // V ds_read swizzled chunk offsets
  int sw1 = sw0 ^ 32;

  // K per-lane fragment base: A-row c holds K row sigma(c)=(c>>2)*8+(c&3);
  // d-chunk quad*8. Per-t row offsets: +(t&1)*4 + (t>>1)*32.
  const unsigned short* kp0 =
      kbase + (size_t)(s * kvlen + (c >> 2) * 8 + (c & 3)) * DH + quad * 8;

  int nIt = kvlen / 64;
  // prologue: stage V(0); load K(0) t=0,1 fragments (t=2,3 loaded in-loop)
  GLD16(vp,            &Vl[0][(w * 16)     * 64]);
  GLD16(vp + 8 * NSEQ, &Vl[0][(w * 16 + 8) * 64]);
  vp += 64;
  bf16x8 k00 = ldb(kp0),          k01 = ldb(kp0 + 32);
  bf16x8 k10 = ldb(kp0 + 4 * DH), k11 = ldb(kp0 + 4 * DH + 32);

  union U4 { unsigned u[4]; bf16x8 v; };

  for (int it = 0; it < nIt; it++) {
    int cur = it & 1;
    __syncthreads();   // V(it) ready in Vl[cur]; prior Vl reads done
    if (it + 1 < nIt) {
      int nb = cur ^ 1;
      GLD16(vp,            &Vl[nb][(w * 16)     * 64]);   // V(it+1)
      GLD16(vp + 8 * NSEQ, &Vl[nb][(w * 16 + 8) * 64]);
      vp += 64;
    }
    // t=2,3 K fragments of current tile (hidden under t=0,1 compute)
    const unsigned short* kq = kp0 + 32 * DH;
    bf16x8 k20 = ldb(kq),          k21 = ldb(kq + 32);
    bf16x8 k30 = ldb(kq + 4 * DH), k31 = ldb(kq + 4 * DH + 32);

    // ---- QK: z_t[rr] = S[q-row][j = quad*8 + (t&1)*4 + rr + (t>>1)*32] ----
    U4 plo0, plo1, phi0, phi1;
    {
      __builtin_amdgcn_s_setprio(1);
      f32x4 zl0 = {}; zl0 = mm(k00, qlo0, zl0); zl0 = mm(k01, qlo1, zl0);
      f32x4 zh0 = {}; zh0 = mm(k00, qhi0, zh0); zh0 = mm(k01, qhi1, zh0);
      f32x4 zl1 = {}; zl1 = mm(k10, qlo0, zl1); zl1 = mm(k11, qlo1, zl1);
      f32x4 zh1 = {}; zh1 = mm(k10, qhi0, zh1); zh1 = mm(k11, qhi1, zh1);
      __builtin_amdgcn_s_setprio(0);
      plo0.u[0] = cvtpk(ex2(zl0[0]), ex2(zl0[1]));
      plo0.u[1] = cvtpk(ex2(zl0[2]), ex2(zl0[3]));
      plo0.u[2] = cvtpk(ex2(zl1[0]), ex2(zl1[1]));
      plo0.u[3] = cvtpk(ex2(zl1[2]), ex2(zl1[3]));
      phi0.u[0] = cvtpk(ex2(zh0[0]), ex2(zh0[1]));
      phi0.u[1] = cvtpk(ex2(zh0[2]), ex2(zh0[3]));
      phi0.u[2] = cvtpk(ex2(zh1[0]), ex2(zh1[1]));
      phi0.u[3] = cvtpk(ex2(zh1[2]), ex2(zh1[3]));
    }
    {
      __builtin_amdgcn_s_setprio(1);
      f32x4 zl2 = {}; zl2 = mm(k20, qlo0, zl2); zl2 = mm(k21, qlo1, zl2);
      f32x4 zh2 = {}; zh2 = mm(k20, qhi0, zh2); zh2 = mm(k21, qhi1, zh2);
      f32x4 zl3 = {}; zl3 = mm(k30, qlo0, zl3); zl3 = mm(k31, qlo1, zl3);
      f32x4 zh3 = {}; zh3 = mm(k30, qhi0, zh3); zh3 = mm(k31, qhi1, zh3);
      __builtin_amdgcn_s_setprio(0);
      plo1.u[0] = cvtpk(ex2(zl2[0]), ex2(zl2[1]));
      plo1.u[1] = cvtpk(ex2(zl2[2]), ex2(zl2[3]));
      plo1.u[2] = cvtpk(ex2(zl3[0]), ex2(zl3[1]));
      plo1.u[3] = cvtpk(ex2(zl3[2]), ex2(zl3[3]));
      phi1.u[0] = cvtpk(ex2(zh2[0]), ex2(zh2[1]));
      phi1.u[1] = cvtpk(ex2(zh2[2]), ex2(zh2[3]));
      phi1.u[2] = cvtpk(ex2(zh3[0]), ex2(zh3[1]));
      phi1.u[3] = cvtpk(ex2(zh3[2]), ex2(zh3[3]));
    }

    // prefetch K(it+1) t=0,1 fragments (land during PV); guarded so the
    // last iteration never reads past the segment end
    if (it + 1 < nIt) {
      kp0 += 64 * DH;
      k00 = ldb(kp0);          k01 = ldb(kp0 + 32);
      k10 = ldb(kp0 + 4 * DH); k11 = ldb(kp0 + 4 * DH + 32);
    }

    // ---- PV ----
#pragma unroll
    for (int dt = 0; dt < 4; dt++) {
      bf16x8 v0 = ldb(&Vl[cur][(dt * 16 + c) * 64 + sw0]);
      bf16x8 v1 = ldb(&Vl[cur][(dt * 16 + c) * 64 + sw1]);
      __builtin_amdgcn_s_setprio(1);
      acclo[dt] = mm(plo0.v, v0, acclo[dt]);
      acclo[dt] = mm(plo1.v, v1, acclo[dt]);
      acchi[dt] = mm(phi0.v, v0, acchi[dt]);
      acchi[dt] = mm(phi1.v, v1, acchi[dt]);
      __builtin_amdgcn_s_setprio(0);
    }
    __builtin_amdgcn_s_setprio(1);
    accllo = mm(plo0.v, ones, accllo); accllo = mm(plo1.v, ones, accllo);
    acclhi = mm(phi0.v, ones, acclhi); acclhi = mm(phi1.v, ones, acclhi);
    __builtin_amdgcn_s_setprio(0);
  }

  size_t rb = ((size_t)(b * NH + h) * S + s) * NSEQ + i0 + w * 32;
  if (c == 0) {
#pragma unroll
    for (int rr = 0; rr < 4; rr++) {
      lpart[rb + quad * 4 + rr]      = accllo[rr];
      lpart[rb + 16 + quad * 4 + rr] = acclhi[rr];
    }
  }
#pragma unroll
  for (int rr = 0; rr < 4; rr++)
#pragma unroll
    for (int dt = 0; dt < 4; dt++) {
      opart[(rb + quad * 4 + rr) * 64 + dt * 16 + c]      = f2bfr(acclo[dt][rr]);
      opart[(rb + 16 + quad * 4 + rr) * 64 + dt * 16 + c] = f2bfr(acchi[dt][rr]);
    }
}

// ------ Kernel 3b: merge split-KV partials (plain sums) -> ao bf16 ----------
__global__ __launch_bounds__(256) void k_merge(
    const unsigned short* __restrict__ opart,
    const float* __restrict__ lpart,
    unsigned short* __restrict__ ao, int S) {
  int t = blockIdx.x * 256 + threadIdx.x;     // 131072 threads
  int row = t >> 2;                            // (b*NH+h)*NSEQ + i
  int dseg = (t & 3) * 16;
  int b = row >> 14, rem = row & 16383;
  int h = rem >> 12, i = rem & 4095;

  float l = 0.f;
  float o[16];
#pragma unroll
  for (int j = 0; j < 16; j++) o[j] = 0.f;
  for (int s = 0; s < S; s++) {
    size_t rb = ((size_t)(b * NH + h) * S + s) * NSEQ + i;
    l += lpart[rb];
    const unsigned short* p = opart + rb * 64 + dseg;
    u16x8 v0 = *(const u16x8*)p;
    u16x8 v1 = *(const u16x8*)(p + 8);
#pragma unroll
    for (int j = 0; j < 8; j++) {
      o[j]     += bf2f(v0[j]);
      o[8 + j] += bf2f(v1[j]);
    }
  }
  float inv = 1.f / l;
  unsigned short* dst = ao + ((size_t)b * NSEQ + i) * INNER + h * 64 + dseg;
  uint4 pk0 = { pack2(o[0] * inv, o[1] * inv),  pack2(o[2] * inv, o[3] * inv),
                pack2(o[4] * inv, o[5] * inv),  pack2(o[6] * inv, o[7] * inv) };
  uint4 pk1 = { pack2(o[8] * inv, o[9] * inv),  pack2(o[10] * inv, o[11] * inv),
                pack2(o[12] * inv, o[13] * inv),pack2(o[14] * inv, o[15] * inv) };
  *(uint4*)dst = pk0;
  *(uint4*)(dst + 8) = pk1;
}

// ------ Kernel 4: out-proj + residual, full-K staging (1 main barrier) ------
__global__ __launch_bounds__(256) void k_out(const unsigned short* __restrict__ wob,
                                             const unsigned short* __restrict__ ao,
                                             const float* __restrict__ x,
                                             float* __restrict__ out) {
  int n0 = blockIdx.x * 64;
  int o0 = blockIdx.y * 64;
  int b  = blockIdx.z;
  __shared__ unsigned short Al[64 * 256];   // 32 KB
  __shared__ unsigned short Bl[64 * 256];   // 32 KB
  int t = threadIdx.x;
  int lane = t & 63, w = t >> 6;
  int c = lane & 15, quad = lane >> 4;
  int wm = w >> 1, wn = w & 1;
  f32x4 acc[2][2] = {};
  int lr2 = lane >> 5;
  int lch = lane & 31;
  const unsigned short* apg = wob + (size_t)o0 * INNER;
  const unsigned short* bpg = ao + ((size_t)b * NSEQ + n0) * INNER;
#pragma unroll
  for (int q = 0; q < 8; q++) {
    int r = w * 16 + q * 2 + lr2;
    int srcoff = r * INNER + ((lch ^ (r & 7)) * 8);
    GLD16(apg + srcoff, Al + (size_t)(w * 16 + q * 2) * 256);
    GLD16(bpg + srcoff, Bl + (size_t)(w * 16 + q * 2) * 256);
  }
  __syncthreads();
#pragma unroll
  for (int ks = 0; ks < 8; ks++) {
    int ra0 = wm * 32 + c, ra1 = ra0 + 16;
    int rb0 = wn * 32 + c, rb1 = rb0 + 16;
    bf16x8 a0 = ldb(&Al[ra0 * 256 + (((ks * 4 + quad) ^ (ra0 & 7)) * 8)]);
    bf16x8 a1 = ldb(&Al[ra1 * 256 + (((ks * 4 + quad) ^ (ra1 & 7)) * 8)]);
    bf16x8 b0 = ldb(&Bl[rb0 * 256 + (((ks * 4 + quad) ^ (rb0 & 7)) * 8)]);
    bf16x8 b1 = ldb(&Bl[rb1 * 256 + (((ks * 4 + quad) ^ (rb1 & 7)) * 8)]);
    acc[0][0] = mm(a0, b0, acc[0][0]);
    acc[0][1] = mm(a0, b1, acc[0][1]);
    acc[1][0] = mm(a1, b0, acc[1][0]);
    acc[1][1] = mm(a1, b1, acc[1][1]);
  }
#pragma unroll
  for (int i = 0; i < 2; i++)
#pragma unroll
    for (int j = 0; j < 2; j++)
#pragma unroll
      for (int rr = 0; rr < 4; rr++) {
        int o = o0 + wm * 32 + i * 16 + quad * 4 + rr;
        int n = n0 + wn * 32 + j * 16 + c;
        size_t idx = ((size_t)b * CCH + o) * NSEQ + n;
        out[idx] = acc[i][j][rr] + x[idx];
      }
}

extern "C" void kernel_launch(void* const* d_in, const int* in_sizes, int n_in,
                              void* d_out, int out_size, void* d_ws, size_t ws_size,
                              hipStream_t stream) {
  const float* x     = (const float*)d_in[0];
  const float* gamma = (const float*)d_in[1];
  const float* wq    = (const float*)d_in[2];
  const float* wo    = (const float*)d_in[3];
  float* out = (float*)d_out;

  const size_t MB = 1u << 20;
  char* ws = (char*)d_ws;
  // ws layout:
  unsigned short* ao  = (unsigned short*)ws;                   // [0,4)  bf16 [B][N][256]
  unsigned short* xn  = (unsigned short*)(ws + 4 * MB);        // [4,8)  bf16 [B][N][256]
  unsigned short* qkv = (unsigned short*)(ws + 8 * MB);        // [8,20) bf16 [B][768][N] (v region used)
  unsigned short* wqb = (unsigned short*)(ws + 20 * MB);       // 384 KB
  unsigned short* wob = (unsigned short*)(ws + 20 * MB + 512 * 1024); // 128 KB
  unsigned short* qt  = (unsigned short*)(ws + 21 * MB);       // [21,25) bf16 [B][H][N][D]
  unsigned short* ktb = (unsigned short*)(ws + 25 * MB);       // [25,29) bf16 [B][H][N][D]
  unsigned short* opart = (unsigned short*)(ws + 29 * MB);     // S*B*H*N*64 bf16
  int S;
  if (ws_size >= 48 * MB) S = 4;
  else if (ws_size >= 40 * MB) S = 2;
  else S = 1;
  size_t opart_bytes = (size_t)S * BATCH * NH * NSEQ * DH * 2;
  float* lpart = (float*)(ws + 29 * MB + opart_bytes);
  int kvlen = NSEQ / S;

  k_lncvt<<<dim3(512),          256, 0, stream>>>(x, gamma, xn, wq, wo, wqb, wob);
  k_qkv  <<<dim3(64, 12, 2),    256, 0, stream>>>(wqb, xn, qkv, qt, ktb);
  k_attn <<<dim3(32, 4, 2 * S), 256, 0, stream>>>(qt, ktb, qkv, opart,
                                                  lpart, S, kvlen);
  k_merge<<<dim3(512),          256, 0, stream>>>(opart, lpart, ao, S);
  k_out  <<<dim3(64, 4, 2),     256, 0, stream>>>(wob, ao, x, out);
}

// Round 5
// 126.858 us; speedup vs baseline: 1.2328x; 1.2328x over previous
//
#include <hip/hip_runtime.h>

// Problem: B=2, C=256, F*H*W=N=4096, heads=4, dim_head=64, inner=256
#define BATCH 2
#define CCH   256
#define NSEQ  4096
#define NH    4
#define DH    64
#define INNER 256

typedef __attribute__((ext_vector_type(8))) __bf16 bf16x8;
typedef __attribute__((ext_vector_type(4))) float f32x4;
typedef __attribute__((ext_vector_type(8))) unsigned short u16x8;
typedef __attribute__((ext_vector_type(4))) unsigned short u16x4;

// async global->LDS, 16B per lane; LDS dest = wave-uniform base + lane*16
#define GLD16(gsrc, ldst)                                                     \
  __builtin_amdgcn_global_load_lds(                                           \
      (const __attribute__((address_space(1))) unsigned int*)(const void*)(gsrc), \
      (__attribute__((address_space(3))) unsigned int*)(void*)(ldst), 16, 0, 0)

// round-half-up bf16 (inputs finite; <=0.5ulp bias vs RNE, irrelevant here)
static __device__ __forceinline__ unsigned short f2bfr(float f) {
  union { float f; unsigned u; } v; v.f = f;
  return (unsigned short)((v.u + 0x8000u) >> 16);
}
// pack two floats -> bf16 pair (low = f0) via v_perm_b32: 3 VALU ops
static __device__ __forceinline__ unsigned pack2(float f0, float f1) {
  union { float f; unsigned u; } a, b; a.f = f0; b.f = f1;
  return __builtin_amdgcn_perm(b.u + 0x8000u, a.u + 0x8000u, 0x07060302u);
}
// 1-op pack: v_cvt_pk_bf16_f32 (RNE; fine at bf16 tolerance)
static __device__ __forceinline__ unsigned cvtpk(float lo, float hi) {
  unsigned r;
  asm("v_cvt_pk_bf16_f32 %0, %1, %2" : "=v"(r) : "v"(lo), "v"(hi));
  return r;
}
static __device__ __forceinline__ float bf2f(unsigned short u) {
  union { unsigned u; float f; } v; v.u = ((unsigned)u) << 16;
  return v.f;
}
static __device__ __forceinline__ bf16x8 ldb(const unsigned short* p) {
  return *(const bf16x8*)p;
}
static __device__ __forceinline__ f32x4 mm(bf16x8 a, bf16x8 b, f32x4 c) {
  return __builtin_amdgcn_mfma_f32_16x16x32_bf16(a, b, c, 0, 0, 0);
}
// raw v_exp_f32: inputs bounded to |x| <= ~11.6, no denormal fixup needed
static __device__ __forceinline__ float ex2(float x) {
  return __builtin_amdgcn_exp2f(x);
}

// ------ Kernel 1: LN -> xn [b][n][c] bf16  (+ fused fp32->bf16 weight cvt) --
__global__ __launch_bounds__(256) void k_lncvt(const float* __restrict__ x,
                                               const float* __restrict__ gamma,
                                               unsigned short* __restrict__ xn,
                                               const float* __restrict__ wq,
                                               const float* __restrict__ wo,
                                               unsigned short* __restrict__ wqb,
                                               unsigned short* __restrict__ wob) {
  int blk = blockIdx.x;
  if (blk >= 256) {                       // weight convert: 256 blocks
    int t = (blk - 256) * 256 + threadIdx.x;
    int e = t * 4;
    if (e < 768 * 256) {
      float4 v = *(const float4*)(wq + e);
      u16x4 pk = { f2bfr(v.x), f2bfr(v.y), f2bfr(v.z), f2bfr(v.w) };
      *(u16x4*)(wqb + e) = pk;
    } else {
      int e2 = e - 768 * 256;
      float4 v = *(const float4*)(wo + e2);
      u16x4 pk = { f2bfr(v.x), f2bfr(v.y), f2bfr(v.z), f2bfr(v.w) };
      *(u16x4*)(wob + e2) = pk;
    }
    return;
  }
  int b  = blk >> 7;
  int n0 = (blk & 127) * 32;
  int t  = threadIdx.x;
  int nl = t & 31;
  int cg = t >> 5;                 // channel group 0..7 (32 channels each)
  int n  = n0 + nl;
  const float* xp = x + ((size_t)(b * CCH + cg * 32)) * NSEQ + n;
  float vals[32];
  float s = 0.f, s2 = 0.f;
#pragma unroll
  for (int j = 0; j < 32; j++) {
    float v = xp[(size_t)j * NSEQ];
    vals[j] = v; s += v; s2 += v * v;
  }
  __shared__ float rs[8][32], rs2[8][32];
  rs[cg][nl] = s; rs2[cg][nl] = s2;
  __syncthreads();
  float S = 0.f, S2 = 0.f;
#pragma unroll
  for (int g = 0; g < 8; g++) { S += rs[g][nl]; S2 += rs2[g][nl]; }
  float mean = S * (1.f / 256.f);
  float var  = S2 * (1.f / 256.f) - mean * mean;
  float rstd = rsqrtf(var + 1e-5f);
  unsigned short* dst = xn + ((size_t)b * NSEQ + n) * CCH + cg * 32;
#pragma unroll
  for (int j0 = 0; j0 < 32; j0 += 8) {
    u16x8 pk;
#pragma unroll
    for (int j = 0; j < 8; j++)
      pk[j] = f2bfr((vals[j0 + j] - mean) * rstd * gamma[cg * 32 + j0 + j]);
    *(u16x8*)(dst + j0) = pk;
  }
}

// --- Kernel 2: QKV GEMM + fused l2norm, BK=128 (3 barriers total) ----------
// Tiles staged via global_load_lds into stride-128 rows, XOR chunk swizzle.
// oi 0..3: q head oi -> qt (scaled 8*log2e); 4..7: k -> ktb; 8..11: v -> qkv.
__global__ __launch_bounds__(256) void k_qkv(const unsigned short* __restrict__ wqb,
                                             const unsigned short* __restrict__ xn,
                                             unsigned short* __restrict__ qkv,
                                             unsigned short* __restrict__ qt,
                                             unsigned short* __restrict__ ktb) {
  int n0 = blockIdx.x * 64;
  int oi = blockIdx.y;
  int o0 = oi * 64;
  int b  = blockIdx.z;
  __shared__ unsigned short Al[64 * 128];   // [o][k-local] swizzled, 16 KB
  __shared__ unsigned short Bl[64 * 128];   // [n][k-local] swizzled, 16 KB
  int t = threadIdx.x;
  int lane = t & 63, w = t >> 6;
  int c = lane & 15, quad = lane >> 4;
  int wm = w >> 1, wn = w & 1;
  f32x4 acc[2][2] = {};
  int lr = lane >> 4;                       // row within 4-row group
  int lchk = lane & 15;                     // phys chunk (16 chunks/row)
  const unsigned short* apg = wqb + (size_t)o0 * CCH;
  const unsigned short* bpg = xn + ((size_t)b * NSEQ + n0) * CCH;
  for (int kt = 0; kt < 2; kt++) {
    if (kt) __syncthreads();
#pragma unroll
    for (int q = 0; q < 4; q++) {
      int r = w * 16 + q * 4 + lr;
      int srcoff = r * CCH + kt * 128 + ((lchk ^ (r & 7)) * 8);
      GLD16(apg + srcoff, Al + (size_t)(w * 16 + q * 4) * 128);
      GLD16(bpg + srcoff, Bl + (size_t)(w * 16 + q * 4) * 128);
    }
    __syncthreads();
#pragma unroll
    for (int ks = 0; ks < 4; ks++) {
      int ra0 = wm * 32 + c, ra1 = ra0 + 16;
      int rb0 = wn * 32 + c, rb1 = rb0 + 16;
      bf16x8 a0 = ldb(&Al[ra0 * 128 + (((ks * 4 + quad) ^ (ra0 & 7)) * 8)]);
      bf16x8 a1 = ldb(&Al[ra1 * 128 + (((ks * 4 + quad) ^ (ra1 & 7)) * 8)]);
      bf16x8 b0 = ldb(&Bl[rb0 * 128 + (((ks * 4 + quad) ^ (rb0 & 7)) * 8)]);
      bf16x8 b1 = ldb(&Bl[rb1 * 128 + (((ks * 4 + quad) ^ (rb1 & 7)) * 8)]);
      acc[0][0] = mm(a0, b0, acc[0][0]);
      acc[0][1] = mm(a0, b1, acc[0][1]);
      acc[1][0] = mm(a1, b0, acc[1][0]);
      acc[1][1] = mm(a1, b1, acc[1][1]);
    }
  }
  if (oi < 8) {
    // per-n sum of squares: this wave covers d in [wm*32, wm*32+32)
    float* sq = (float*)Al;                 // reuse Al after final reads
    float s0 = 0.f, s1 = 0.f;
#pragma unroll
    for (int i = 0; i < 2; i++)
#pragma unroll
      for (int rr = 0; rr < 4; rr++) {
        s0 += acc[i][0][rr] * acc[i][0][rr];
        s1 += acc[i][1][rr] * acc[i][1][rr];
      }
    s0 += __shfl_xor(s0, 16); s0 += __shfl_xor(s0, 32);
    s1 += __shfl_xor(s1, 16); s1 += __shfl_xor(s1, 32);
    __syncthreads();
    if (quad == 0) {
      sq[wm * 64 + wn * 32 + c]      = s0;
      sq[wm * 64 + wn * 32 + 16 + c] = s1;
    }
    __syncthreads();
    float r0 = rsqrtf(sq[wn * 32 + c]      + sq[64 + wn * 32 + c]      + 1e-12f);
    float r1 = rsqrtf(sq[wn * 32 + 16 + c] + sq[64 + wn * 32 + 16 + c] + 1e-12f);
    if (oi < 4) { r0 *= 11.541560327111707f; r1 *= 11.541560327111707f; } // 8*log2e
    int h = oi & 3;
    unsigned short* base = (oi < 4 ? qt : ktb) + ((size_t)(b * NH + h) * NSEQ) * DH;
#pragma unroll
    for (int i = 0; i < 2; i++)
#pragma unroll
      for (int j = 0; j < 2; j++) {
        float rsc = j ? r1 : r0;
        int n = n0 + wn * 32 + j * 16 + c;
        int d = wm * 32 + i * 16 + quad * 4;
        uint2 pk = { pack2(acc[i][j][0] * rsc, acc[i][j][1] * rsc),
                     pack2(acc[i][j][2] * rsc, acc[i][j][3] * rsc) };
        *(uint2*)(base + (size_t)n * DH + d) = pk;
      }
  } else {
#pragma unroll
    for (int i = 0; i < 2; i++)
#pragma unroll
      for (int j = 0; j < 2; j++)
#pragma unroll
        for (int rr = 0; rr < 4; rr++) {
          int o = o0 + wm * 32 + i * 16 + quad * 4 + rr;
          int n = n0 + wn * 32 + j * 16 + c;
          qkv[((size_t)b * 768 + o) * NSEQ + n] = f2bfr(acc[i][j][rr]);
        }
  }
}

// ------ Kernel 3: flash attention, hybrid ----------------------------------
// K AND V both GLD16-staged, double-buffered (prefetch issued right after the
// single per-iter barrier, consumed after the NEXT barrier -> full-iteration
// latency cover; R4 showed direct-global K exposes L2 latency and collapses
// MfmaUtil to 19%). P never touches LDS: QK uses row-permuted K (A-row a
// holds K row sigma_t(a)=(a>>2)*8+(a&3)+(t&1)*4+(t>>1)*32) so each lane's
// cvt_pk(exp2(z)) IS its PV A-fragment (verified correct in R4).
// K staging uses a custom XOR swizzle f(r)=(r&3)|(((r>>3)&1)<<2) matched to
// the permuted read -> 2-way bank aliasing (free). LDS 32 KB, 4 blocks/CU.
__global__ __launch_bounds__(256, 4) void k_attn(
    const unsigned short* __restrict__ qt,
    const unsigned short* __restrict__ ktb,
    const unsigned short* __restrict__ qkv,
    unsigned short* __restrict__ opart,
    float* __restrict__ lpart,
    int S, int kvlen) {
  int i0 = blockIdx.x * 128;
  int h  = blockIdx.y;
  int bz = blockIdx.z;
  int b  = bz / S, s = bz % S;
  __shared__ unsigned short Kl[2][64 * 64];  // [j][d] f-swizzled, 2x8 KB
  __shared__ unsigned short Vl[2][64 * 64];  // [d][j] swizzled, 2x8 KB
  int t = threadIdx.x;
  int lane = t & 63, w = t >> 6;
  int c = lane & 15, quad = lane >> 4;

  const unsigned short* qbase = qt  + ((size_t)(b * NH + h) * NSEQ) * DH;
  const unsigned short* kbase = ktb + ((size_t)(b * NH + h) * NSEQ) * DH;
  const unsigned short* vbase = qkv + ((size_t)b * 768 + 512 + h * 64) * NSEQ;

  // Q fragments straight from global (one-time, L2-served)
  int rlo = w * 32 + c, rhi = rlo + 16;     // local q-rows of this lane
  const unsigned short* qlo = qbase + (size_t)(i0 + rlo) * DH + quad * 8;
  const unsigned short* qhi = qlo + 16 * DH;
  bf16x8 qlo0 = ldb(qlo), qlo1 = ldb(qlo + 32);
  bf16x8 qhi0 = ldb(qhi), qhi1 = ldb(qhi + 32);

  u16x8 onesu;
#pragma unroll
  for (int j = 0; j < 8; j++) onesu[j] = 0x3F80;               // bf16 1.0
  bf16x8 ones = *(bf16x8*)&onesu;

  f32x4 acclo[4] = {}, acchi[4] = {};
  f32x4 accllo = {}, acclhi = {};

  // staging: lane covers row w*16 + {0,8} + (lane>>3), phys chunk lane&7
  int slr = lane >> 3, slc = lane & 7;
  int ssw_v  = (slc ^ slr) * 8;             // V source swizzle (f_v(r)=r&7)
  int ssw_k1 = (slc ^ (slr & 3)) * 8;       // K rows u=0..7  (f=u&3)
  int ssw_k2 = ssw_k1 ^ 32;                 // K rows u=8..15 (f=(u&3)|4)
  const unsigned short* kp = kbase + (size_t)(s * kvlen + w * 16 + slr) * DH;
  const unsigned short* vp = vbase + (size_t)(w * 16 + slr) * NSEQ + s * kvlen + ssw_v;
  int sw0 = (quad ^ (c & 7)) * 8;           // V ds_read swizzled chunk offsets
  int sw1 = sw0 ^ 32;
  // K permuted read: row sigma_t(c), f(sigma_t(c)) = (c&3)|(((c>>2)&1)<<2)
  int fK    = (c & 3) | (((c >> 2) & 1) << 2);
  int swk0  = (quad ^ fK) * 8;
  int swk1  = swk0 ^ 32;
  int krow0 = (c >> 2) * 8 + (c & 3);

  int nIt = kvlen / 64;
  // prologue: stage K(0), V(0) into buffer 0
  GLD16(kp + ssw_k1,          &Kl[0][(w * 16)     * 64]);
  GLD16(kp + 8 * DH + ssw_k2, &Kl[0][(w * 16 + 8) * 64]);
  GLD16(vp,                   &Vl[0][(w * 16)     * 64]);
  GLD16(vp + 8 * NSEQ,        &Vl[0][(w * 16 + 8) * 64]);
  kp += 64 * DH; vp += 64;

  union U4 { unsigned u[4]; bf16x8 v; };

  for (int it = 0; it < nIt; it++) {
    int cur = it & 1;
    __syncthreads();   // vmcnt(0) drain: K(it)+V(it) ready; prior reads done
    if (it + 1 < nIt) {
      int nb = cur ^ 1;
      GLD16(kp + ssw_k1,          &Kl[nb][(w * 16)     * 64]);
      GLD16(kp + 8 * DH + ssw_k2, &Kl[nb][(w * 16 + 8) * 64]);
      GLD16(vp,                   &Vl[nb][(w * 16)     * 64]);
      GLD16(vp + 8 * NSEQ,        &Vl[nb][(w * 16 + 8) * 64]);
      kp += 64 * DH; vp += 64;
    }

    // K fragments from LDS (permuted rows; 2-way bank aliasing = free)
    const unsigned short* Kb = &Kl[cur][0];
    bf16x8 k00 = ldb(&Kb[(krow0)      * 64 + swk0]);
    bf16x8 k01 = ldb(&Kb[(krow0)      * 64 + swk1]);
    bf16x8 k10 = ldb(&Kb[(krow0 + 4)  * 64 + swk0]);
    bf16x8 k11 = ldb(&Kb[(krow0 + 4)  * 64 + swk1]);
    bf16x8 k20 = ldb(&Kb[(krow0 + 32) * 64 + swk0]);
    bf16x8 k21 = ldb(&Kb[(krow0 + 32) * 64 + swk1]);
    bf16x8 k30 = ldb(&Kb[(krow0 + 36) * 64 + swk0]);
    bf16x8 k31 = ldb(&Kb[(krow0 + 36) * 64 + swk1]);

    // ---- QK: z_t[rr] = S[q-row][j = quad*8 + (t&1)*4 + rr + (t>>1)*32] ----
    U4 plo0, plo1, phi0, phi1;
    {
      __builtin_amdgcn_s_setprio(1);
      f32x4 zl0 = {}; zl0 = mm(k00, qlo0, zl0); zl0 = mm(k01, qlo1, zl0);
      f32x4 zh0 = {}; zh0 = mm(k00, qhi0, zh0); zh0 = mm(k01, qhi1, zh0);
      f32x4 zl1 = {}; zl1 = mm(k10, qlo0, zl1); zl1 = mm(k11, qlo1, zl1);
      f32x4 zh1 = {}; zh1 = mm(k10, qhi0, zh1); zh1 = mm(k11, qhi1, zh1);
      __builtin_amdgcn_s_setprio(0);
      plo0.u[0] = cvtpk(ex2(zl0[0]), ex2(zl0[1]));
      plo0.u[1] = cvtpk(ex2(zl0[2]), ex2(zl0[3]));
      plo0.u[2] = cvtpk(ex2(zl1[0]), ex2(zl1[1]));
      plo0.u[3] = cvtpk(ex2(zl1[2]), ex2(zl1[3]));
      phi0.u[0] = cvtpk(ex2(zh0[0]), ex2(zh0[1]));
      phi0.u[1] = cvtpk(ex2(zh0[2]), ex2(zh0[3]));
      phi0.u[2] = cvtpk(ex2(zh1[0]), ex2(zh1[1]));
      phi0.u[3] = cvtpk(ex2(zh1[2]), ex2(zh1[3]));
    }
    {
      __builtin_amdgcn_s_setprio(1);
      f32x4 zl2 = {}; zl2 = mm(k20, qlo0, zl2); zl2 = mm(k21, qlo1, zl2);
      f32x4 zh2 = {}; zh2 = mm(k20, qhi0, zh2); zh2 = mm(k21, qhi1, zh2);
      f32x4 zl3 = {}; zl3 = mm(k30, qlo0, zl3); zl3 = mm(k31, qlo1, zl3);
      f32x4 zh3 = {}; zh3 = mm(k30, qhi0, zh3); zh3 = mm(k31, qhi1, zh3);
      __builtin_amdgcn_s_setprio(0);
      plo1.u[0] = cvtpk(ex2(zl2[0]), ex2(zl2[1]));
      plo1.u[1] = cvtpk(ex2(zl2[2]), ex2(zl2[3]));
      plo1.u[2] = cvtpk(ex2(zl3[0]), ex2(zl3[1]));
      plo1.u[3] = cvtpk(ex2(zl3[2]), ex2(zl3[3]));
      phi1.u[0] = cvtpk(ex2(zh2[0]), ex2(zh2[1]));
      phi1.u[1] = cvtpk(ex2(zh2[2]), ex2(zh2[3]));
      phi1.u[2] = cvtpk(ex2(zh3[0]), ex2(zh3[1]));
      phi1.u[3] = cvtpk(ex2(zh3[2]), ex2(zh3[3]));
    }

    // ---- PV ----
#pragma unroll
    for (int dt = 0; dt < 4; dt++) {
      bf16x8 v0 = ldb(&Vl[cur][(dt * 16 + c) * 64 + sw0]);
      bf16x8 v1 = ldb(&Vl[cur][(dt * 16 + c) * 64 + sw1]);
      __builtin_amdgcn_s_setprio(1);
      acclo[dt] = mm(plo0.v, v0, acclo[dt]);
      acclo[dt] = mm(plo1.v, v1, acclo[dt]);
      acchi[dt] = mm(phi0.v, v0, acchi[dt]);
      acchi[dt] = mm(phi1.v, v1, acchi[dt]);
      __builtin_amdgcn_s_setprio(0);
    }
    __builtin_amdgcn_s_setprio(1);
    accllo = mm(plo0.v, ones, accllo); accllo = mm(plo1.v, ones, accllo);
    acclhi = mm(phi0.v, ones, acclhi); acclhi = mm(phi1.v, ones, acclhi);
    __builtin_amdgcn_s_setprio(0);
  }

  size_t rb = ((size_t)(b * NH + h) * S + s) * NSEQ + i0 + w * 32;
  if (c == 0) {
#pragma unroll
    for (int rr = 0; rr < 4; rr++) {
      lpart[rb + quad * 4 + rr]      = accllo[rr];
      lpart[rb + 16 + quad * 4 + rr] = acclhi[rr];
    }
  }
#pragma unroll
  for (int rr = 0; rr < 4; rr++)
#pragma unroll
    for (int dt = 0; dt < 4; dt++) {
      opart[(rb + quad * 4 + rr) * 64 + dt * 16 + c]      = f2bfr(acclo[dt][rr]);
      opart[(rb + 16 + quad * 4 + rr) * 64 + dt * 16 + c] = f2bfr(acchi[dt][rr]);
    }
}

// ------ Kernel 3b: merge split-KV partials (plain sums) -> ao bf16 ----------
__global__ __launch_bounds__(256) void k_merge(
    const unsigned short* __restrict__ opart,
    const float* __restrict__ lpart,
    unsigned short* __restrict__ ao, int S) {
  int t = blockIdx.x * 256 + threadIdx.x;     // 131072 threads
  int row = t >> 2;                            // (b*NH+h)*NSEQ + i
  int dseg = (t & 3) * 16;
  int b = row >> 14, rem = row & 16383;
  int h = rem >> 12, i = rem & 4095;

  float l = 0.f;
  float o[16];
#pragma unroll
  for (int j = 0; j < 16; j++) o[j] = 0.f;
  for (int s = 0; s < S; s++) {
    size_t rb = ((size_t)(b * NH + h) * S + s) * NSEQ + i;
    l += lpart[rb];
    const unsigned short* p = opart + rb * 64 + dseg;
    u16x8 v0 = *(const u16x8*)p;
    u16x8 v1 = *(const u16x8*)(p + 8);
#pragma unroll
    for (int j = 0; j < 8; j++) {
      o[j]     += bf2f(v0[j]);
      o[8 + j] += bf2f(v1[j]);
    }
  }
  float inv = 1.f / l;
  unsigned short* dst = ao + ((size_t)b * NSEQ + i) * INNER + h * 64 + dseg;
  uint4 pk0 = { pack2(o[0] * inv, o[1] * inv),  pack2(o[2] * inv, o[3] * inv),
                pack2(o[4] * inv, o[5] * inv),  pack2(o[6] * inv, o[7] * inv) };
  uint4 pk1 = { pack2(o[8] * inv, o[9] * inv),  pack2(o[10] * inv, o[11] * inv),
                pack2(o[12] * inv, o[13] * inv),pack2(o[14] * inv, o[15] * inv) };
  *(uint4*)dst = pk0;
  *(uint4*)(dst + 8) = pk1;
}

// ------ Kernel 4: out-proj + residual, BK=128 (3 barriers total) ------------
__global__ __launch_bounds__(256) void k_out(const unsigned short* __restrict__ wob,
                                             const unsigned short* __restrict__ ao,
                                             const float* __restrict__ x,
                                             float* __restrict__ out) {
  int n0 = blockIdx.x * 64;
  int o0 = blockIdx.y * 64;
  int b  = blockIdx.z;
  __shared__ unsigned short Al[64 * 128];
  __shared__ unsigned short Bl[64 * 128];
  int t = threadIdx.x;
  int lane = t & 63, w = t >> 6;
  int c = lane & 15, quad = lane >> 4;
  int wm = w >> 1, wn = w & 1;
  f32x4 acc[2][2] = {};
  int lr = lane >> 4;
  int lchk = lane & 15;
  const unsigned short* apg = wob + (size_t)o0 * INNER;
  const unsigned short* bpg = ao + ((size_t)b * NSEQ + n0) * INNER;
  for (int kt = 0; kt < 2; kt++) {
    if (kt) __syncthreads();
#pragma unroll
    for (int q = 0; q < 4; q++) {
      int r = w * 16 + q * 4 + lr;
      int srcoff = r * INNER + kt * 128 + ((lchk ^ (r & 7)) * 8);
      GLD16(apg + srcoff, Al + (size_t)(w * 16 + q * 4) * 128);
      GLD16(bpg + srcoff, Bl + (size_t)(w * 16 + q * 4) * 128);
    }
    __syncthreads();
#pragma unroll
    for (int ks = 0; ks < 4; ks++) {
      int ra0 = wm * 32 + c, ra1 = ra0 + 16;
      int rb0 = wn * 32 + c, rb1 = rb0 + 16;
      bf16x8 a0 = ldb(&Al[ra0 * 128 + (((ks * 4 + quad) ^ (ra0 & 7)) * 8)]);
      bf16x8 a1 = ldb(&Al[ra1 * 128 + (((ks * 4 + quad) ^ (ra1 & 7)) * 8)]);
      bf16x8 b0 = ldb(&Bl[rb0 * 128 + (((ks * 4 + quad) ^ (rb0 & 7)) * 8)]);
      bf16x8 b1 = ldb(&Bl[rb1 * 128 + (((ks * 4 + quad) ^ (rb1 & 7)) * 8)]);
      acc[0][0] = mm(a0, b0, acc[0][0]);
      acc[0][1] = mm(a0, b1, acc[0][1]);
      acc[1][0] = mm(a1, b0, acc[1][0]);
      acc[1][1] = mm(a1, b1, acc[1][1]);
    }
  }
#pragma unroll
  for (int i = 0; i < 2; i++)
#pragma unroll
    for (int j = 0; j < 2; j++)
#pragma unroll
      for (int rr = 0; rr < 4; rr++) {
        int o = o0 + wm * 32 + i * 16 + quad * 4 + rr;
        int n = n0 + wn * 32 + j * 16 + c;
        size_t idx = ((size_t)b * CCH + o) * NSEQ + n;
        out[idx] = acc[i][j][rr] + x[idx];
      }
}

extern "C" void kernel_launch(void* const* d_in, const int* in_sizes, int n_in,
                              void* d_out, int out_size, void* d_ws, size_t ws_size,
                              hipStream_t stream) {
  const float* x     = (const float*)d_in[0];
  const float* gamma = (const float*)d_in[1];
  const float* wq    = (const float*)d_in[2];
  const float* wo    = (const float*)d_in[3];
  float* out = (float*)d_out;

  const size_t MB = 1u << 20;
  char* ws = (char*)d_ws;
  // ws layout:
  unsigned short* ao  = (unsigned short*)ws;                   // [0,4)  bf16 [B][N][256]
  unsigned short* xn  = (unsigned short*)(ws + 4 * MB);        // [4,8)  bf16 [B][N][256]
  unsigned short* qkv = (unsigned short*)(ws + 8 * MB);        // [8,20) bf16 [B][768][N] (v region used)
  unsigned short* wqb = (unsigned short*)(ws + 20 * MB);       // 384 KB
  unsigned short* wob = (unsigned short*)(ws + 20 * MB + 512 * 1024); // 128 KB
  unsigned short* qt  = (unsigned short*)(ws + 21 * MB);       // [21,25) bf16 [B][H][N][D]
  unsigned short* ktb = (unsigned short*)(ws + 25 * MB);       // [25,29) bf16 [B][H][N][D]
  unsigned short* opart = (unsigned short*)(ws + 29 * MB);     // S*B*H*N*64 bf16
  int S;
  if (ws_size >= 48 * MB) S = 4;
  else if (ws_size >= 40 * MB) S = 2;
  else S = 1;
  size_t opart_bytes = (size_t)S * BATCH * NH * NSEQ * DH * 2;
  float* lpart = (float*)(ws + 29 * MB + opart_bytes);
  int kvlen = NSEQ / S;

  k_lncvt<<<dim3(512),          256, 0, stream>>>(x, gamma, xn, wq, wo, wqb, wob);
  k_qkv  <<<dim3(64, 12, 2),    256, 0, stream>>>(wqb, xn, qkv, qt, ktb);
  k_attn <<<dim3(32, 4, 2 * S), 256, 0, stream>>>(qt, ktb, qkv, opart,
                                                  lpart, S, kvlen);
  k_merge<<<dim3(512),          256, 0, stream>>>(opart, lpart, ao, S);
  k_out  <<<dim3(64, 4, 2),     256, 0, stream>>>(wob, ao, x, out);
}

// Round 6
// 124.009 us; speedup vs baseline: 1.2611x; 1.0230x over previous
//
#include <hip/hip_runtime.h>

// Problem: B=2, C=256, F*H*W=N=4096, heads=4, dim_head=64, inner=256
#define BATCH 2
#define CCH   256
#define NSEQ  4096
#define NH    4
#define DH    64
#define INNER 256

typedef __attribute__((ext_vector_type(8))) __bf16 bf16x8;
typedef __attribute__((ext_vector_type(4))) float f32x4;
typedef __attribute__((ext_vector_type(8))) unsigned short u16x8;
typedef __attribute__((ext_vector_type(4))) unsigned short u16x4;

// async global->LDS, 16B per lane; LDS dest = wave-uniform base + lane*16
#define GLD16(gsrc, ldst)                                                     \
  __builtin_amdgcn_global_load_lds(                                           \
      (const __attribute__((address_space(1))) unsigned int*)(const void*)(gsrc), \
      (__attribute__((address_space(3))) unsigned int*)(void*)(ldst), 16, 0, 0)

// round-half-up bf16 (inputs finite; <=0.5ulp bias vs RNE, irrelevant here)
static __device__ __forceinline__ unsigned short f2bfr(float f) {
  union { float f; unsigned u; } v; v.f = f;
  return (unsigned short)((v.u + 0x8000u) >> 16);
}
// pack two floats -> bf16 pair (low = f0) via v_perm_b32: 3 VALU ops
static __device__ __forceinline__ unsigned pack2(float f0, float f1) {
  union { float f; unsigned u; } a, b; a.f = f0; b.f = f1;
  return __builtin_amdgcn_perm(b.u + 0x8000u, a.u + 0x8000u, 0x07060302u);
}
// 1-op pack: v_cvt_pk_bf16_f32 (RNE; fine at bf16 tolerance)
static __device__ __forceinline__ unsigned cvtpk(float lo, float hi) {
  unsigned r;
  asm("v_cvt_pk_bf16_f32 %0, %1, %2" : "=v"(r) : "v"(lo), "v"(hi));
  return r;
}
static __device__ __forceinline__ float bf2f(unsigned short u) {
  union { unsigned u; float f; } v; v.u = ((unsigned)u) << 16;
  return v.f;
}
static __device__ __forceinline__ bf16x8 ldb(const unsigned short* p) {
  return *(const bf16x8*)p;
}
static __device__ __forceinline__ f32x4 mm(bf16x8 a, bf16x8 b, f32x4 c) {
  return __builtin_amdgcn_mfma_f32_16x16x32_bf16(a, b, c, 0, 0, 0);
}
// raw v_exp_f32: inputs bounded to |x| <= ~11.6, no denormal fixup needed
static __device__ __forceinline__ float ex2(float x) {
  return __builtin_amdgcn_exp2f(x);
}

// ------ Kernel 1: LN -> xn [b][n][c] bf16  (+ fused fp32->bf16 weight cvt) --
__global__ __launch_bounds__(256) void k_lncvt(const float* __restrict__ x,
                                               const float* __restrict__ gamma,
                                               unsigned short* __restrict__ xn,
                                               const float* __restrict__ wq,
                                               const float* __restrict__ wo,
                                               unsigned short* __restrict__ wqb,
                                               unsigned short* __restrict__ wob) {
  int blk = blockIdx.x;
  if (blk >= 256) {                       // weight convert: 256 blocks
    int t = (blk - 256) * 256 + threadIdx.x;
    int e = t * 4;
    if (e < 768 * 256) {
      float4 v = *(const float4*)(wq + e);
      u16x4 pk = { f2bfr(v.x), f2bfr(v.y), f2bfr(v.z), f2bfr(v.w) };
      *(u16x4*)(wqb + e) = pk;
    } else {
      int e2 = e - 768 * 256;
      float4 v = *(const float4*)(wo + e2);
      u16x4 pk = { f2bfr(v.x), f2bfr(v.y), f2bfr(v.z), f2bfr(v.w) };
      *(u16x4*)(wob + e2) = pk;
    }
    return;
  }
  int b  = blk >> 7;
  int n0 = (blk & 127) * 32;
  int t  = threadIdx.x;
  int nl = t & 31;
  int cg = t >> 5;                 // channel group 0..7 (32 channels each)
  int n  = n0 + nl;
  const float* xp = x + ((size_t)(b * CCH + cg * 32)) * NSEQ + n;
  float vals[32];
  float s = 0.f, s2 = 0.f;
#pragma unroll
  for (int j = 0; j < 32; j++) {
    float v = xp[(size_t)j * NSEQ];
    vals[j] = v; s += v; s2 += v * v;
  }
  __shared__ float rs[8][32], rs2[8][32];
  rs[cg][nl] = s; rs2[cg][nl] = s2;
  __syncthreads();
  float S = 0.f, S2 = 0.f;
#pragma unroll
  for (int g = 0; g < 8; g++) { S += rs[g][nl]; S2 += rs2[g][nl]; }
  float mean = S * (1.f / 256.f);
  float var  = S2 * (1.f / 256.f) - mean * mean;
  float rstd = rsqrtf(var + 1e-5f);
  unsigned short* dst = xn + ((size_t)b * NSEQ + n) * CCH + cg * 32;
#pragma unroll
  for (int j0 = 0; j0 < 32; j0 += 8) {
    u16x8 pk;
#pragma unroll
    for (int j = 0; j < 8; j++)
      pk[j] = f2bfr((vals[j0 + j] - mean) * rstd * gamma[cg * 32 + j0 + j]);
    *(u16x8*)(dst + j0) = pk;
  }
}

// --- Kernel 2: QKV GEMM + fused l2norm, BK=128 (3 barriers total) ----------
// Tiles staged via global_load_lds into stride-128 rows, XOR chunk swizzle.
// oi 0..3: q head oi -> qt (scaled 8*log2e); 4..7: k -> ktb; 8..11: v -> qkv.
__global__ __launch_bounds__(256) void k_qkv(const unsigned short* __restrict__ wqb,
                                             const unsigned short* __restrict__ xn,
                                             unsigned short* __restrict__ qkv,
                                             unsigned short* __restrict__ qt,
                                             unsigned short* __restrict__ ktb) {
  int n0 = blockIdx.x * 64;
  int oi = blockIdx.y;
  int o0 = oi * 64;
  int b  = blockIdx.z;
  __shared__ unsigned short Al[64 * 128];   // [o][k-local] swizzled, 16 KB
  __shared__ unsigned short Bl[64 * 128];   // [n][k-local] swizzled, 16 KB
  int t = threadIdx.x;
  int lane = t & 63, w = t >> 6;
  int c = lane & 15, quad = lane >> 4;
  int wm = w >> 1, wn = w & 1;
  f32x4 acc[2][2] = {};
  int lr = lane >> 4;                       // row within 4-row group
  int lchk = lane & 15;                     // phys chunk (16 chunks/row)
  const unsigned short* apg = wqb + (size_t)o0 * CCH;
  const unsigned short* bpg = xn + ((size_t)b * NSEQ + n0) * CCH;
  for (int kt = 0; kt < 2; kt++) {
    if (kt) __syncthreads();
#pragma unroll
    for (int q = 0; q < 4; q++) {
      int r = w * 16 + q * 4 + lr;
      int srcoff = r * CCH + kt * 128 + ((lchk ^ (r & 7)) * 8);
      GLD16(apg + srcoff, Al + (size_t)(w * 16 + q * 4) * 128);
      GLD16(bpg + srcoff, Bl + (size_t)(w * 16 + q * 4) * 128);
    }
    __syncthreads();
#pragma unroll
    for (int ks = 0; ks < 4; ks++) {
      int ra0 = wm * 32 + c, ra1 = ra0 + 16;
      int rb0 = wn * 32 + c, rb1 = rb0 + 16;
      bf16x8 a0 = ldb(&Al[ra0 * 128 + (((ks * 4 + quad) ^ (ra0 & 7)) * 8)]);
      bf16x8 a1 = ldb(&Al[ra1 * 128 + (((ks * 4 + quad) ^ (ra1 & 7)) * 8)]);
      bf16x8 b0 = ldb(&Bl[rb0 * 128 + (((ks * 4 + quad) ^ (rb0 & 7)) * 8)]);
      bf16x8 b1 = ldb(&Bl[rb1 * 128 + (((ks * 4 + quad) ^ (rb1 & 7)) * 8)]);
      acc[0][0] = mm(a0, b0, acc[0][0]);
      acc[0][1] = mm(a0, b1, acc[0][1]);
      acc[1][0] = mm(a1, b0, acc[1][0]);
      acc[1][1] = mm(a1, b1, acc[1][1]);
    }
  }
  if (oi < 8) {
    // per-n sum of squares: this wave covers d in [wm*32, wm*32+32)
    float* sq = (float*)Al;                 // reuse Al after final reads
    float s0 = 0.f, s1 = 0.f;
#pragma unroll
    for (int i = 0; i < 2; i++)
#pragma unroll
      for (int rr = 0; rr < 4; rr++) {
        s0 += acc[i][0][rr] * acc[i][0][rr];
        s1 += acc[i][1][rr] * acc[i][1][rr];
      }
    s0 += __shfl_xor(s0, 16); s0 += __shfl_xor(s0, 32);
    s1 += __shfl_xor(s1, 16); s1 += __shfl_xor(s1, 32);
    __syncthreads();
    if (quad == 0) {
      sq[wm * 64 + wn * 32 + c]      = s0;
      sq[wm * 64 + wn * 32 + 16 + c] = s1;
    }
    __syncthreads();
    float r0 = rsqrtf(sq[wn * 32 + c]      + sq[64 + wn * 32 + c]      + 1e-12f);
    float r1 = rsqrtf(sq[wn * 32 + 16 + c] + sq[64 + wn * 32 + 16 + c] + 1e-12f);
    if (oi < 4) { r0 *= 11.541560327111707f; r1 *= 11.541560327111707f; } // 8*log2e
    int h = oi & 3;
    unsigned short* base = (oi < 4 ? qt : ktb) + ((size_t)(b * NH + h) * NSEQ) * DH;
#pragma unroll
    for (int i = 0; i < 2; i++)
#pragma unroll
      for (int j = 0; j < 2; j++) {
        float rsc = j ? r1 : r0;
        int n = n0 + wn * 32 + j * 16 + c;
        int d = wm * 32 + i * 16 + quad * 4;
        uint2 pk = { pack2(acc[i][j][0] * rsc, acc[i][j][1] * rsc),
                     pack2(acc[i][j][2] * rsc, acc[i][j][3] * rsc) };
        *(uint2*)(base + (size_t)n * DH + d) = pk;
      }
  } else {
#pragma unroll
    for (int i = 0; i < 2; i++)
#pragma unroll
      for (int j = 0; j < 2; j++)
#pragma unroll
        for (int rr = 0; rr < 4; rr++) {
          int o = o0 + wm * 32 + i * 16 + quad * 4 + rr;
          int n = n0 + wn * 32 + j * 16 + c;
          qkv[((size_t)b * 768 + o) * NSEQ + n] = f2bfr(acc[i][j][rr]);
        }
  }
}

// ------ Kernel 3: flash attention, Q-tile 256 (4 q-sets/wave) --------------
// LDS-throughput-bound fix: every wave reads the FULL K and V tiles per iter
// regardless of Q rows served, so LDS bytes/work ~ 1/Q-tile. Q 128->256
// halves K-read + V-read + staging bytes per unit work (per-CU LDS time
// ~25us -> ~12.5us). K/V GLD16 double-buffered (full-iter latency cover); P
// stays in registers via row-permuted K (sigma_t(a)=(a>>2)*8+(a&3)+(t&1)*4+
// (t>>1)*32; verified R4/R5). K swizzle f(r)=(r&3)|(((r>>3)&1)<<2) matched
// to permuted read. 2 waves/SIMD (launch_bounds 256,2), 512 blocks = 2/CU.
__global__ __launch_bounds__(256, 2) void k_attn(
    const unsigned short* __restrict__ qt,
    const unsigned short* __restrict__ ktb,
    const unsigned short* __restrict__ qkv,
    unsigned short* __restrict__ opart,
    float* __restrict__ lpart,
    int S, int kvlen) {
  int i0 = blockIdx.x * 256;
  int h  = blockIdx.y;
  int bz = blockIdx.z;
  int b  = bz / S, s = bz % S;
  __shared__ unsigned short Kl[2][64 * 64];  // [j][d] f-swizzled, 2x8 KB
  __shared__ unsigned short Vl[2][64 * 64];  // [d][j] swizzled, 2x8 KB
  int t = threadIdx.x;
  int lane = t & 63, w = t >> 6;
  int c = lane & 15, quad = lane >> 4;

  const unsigned short* qbase = qt  + ((size_t)(b * NH + h) * NSEQ) * DH;
  const unsigned short* kbase = ktb + ((size_t)(b * NH + h) * NSEQ) * DH;
  const unsigned short* vbase = qkv + ((size_t)b * 768 + 512 + h * 64) * NSEQ;

  // Q fragments straight from global (one-time, L2-served); 4 sets of 16 rows
  bf16x8 qa[4], qb[4];
#pragma unroll
  for (int ss = 0; ss < 4; ss++) {
    const unsigned short* qp =
        qbase + (size_t)(i0 + w * 64 + ss * 16 + c) * DH + quad * 8;
    qa[ss] = ldb(qp); qb[ss] = ldb(qp + 32);
  }

  u16x8 onesu;
#pragma unroll
  for (int j = 0; j < 8; j++) onesu[j] = 0x3F80;               // bf16 1.0
  bf16x8 ones = *(bf16x8*)&onesu;

  f32x4 acc[4][4] = {};    // [q-set][dt]
  f32x4 accl[4]  = {};     // [q-set] row-sum

  // staging: lane covers row w*16 + {0,8} + (lane>>3), phys chunk lane&7
  int slr = lane >> 3, slc = lane & 7;
  int ssw_v  = (slc ^ slr) * 8;             // V source swizzle (f_v(r)=r&7)
  int ssw_k1 = (slc ^ (slr & 3)) * 8;       // K rows u=0..7  (f=u&3)
  int ssw_k2 = ssw_k1 ^ 32;                 // K rows u=8..15 (f=(u&3)|4)
  const unsigned short* kp = kbase + (size_t)(s * kvlen + w * 16 + slr) * DH;
  const unsigned short* vp = vbase + (size_t)(w * 16 + slr) * NSEQ + s * kvlen + ssw_v;
  int sw0 = (quad ^ (c & 7)) * 8;           // V ds_read swizzled chunk offsets
  int sw1 = sw0 ^ 32;
  // K permuted read: row sigma_t(c), f(sigma_t(c)) = (c&3)|(((c>>2)&1)<<2)
  int fK    = (c & 3) | (((c >> 2) & 1) << 2);
  int swk0  = (quad ^ fK) * 8;
  int swk1  = swk0 ^ 32;
  int krow0 = (c >> 2) * 8 + (c & 3);

  int nIt = kvlen / 64;
  // prologue: stage K(0), V(0) into buffer 0
  GLD16(kp + ssw_k1,          &Kl[0][(w * 16)     * 64]);
  GLD16(kp + 8 * DH + ssw_k2, &Kl[0][(w * 16 + 8) * 64]);
  GLD16(vp,                   &Vl[0][(w * 16)     * 64]);
  GLD16(vp + 8 * NSEQ,        &Vl[0][(w * 16 + 8) * 64]);
  kp += 64 * DH; vp += 64;

  union U4 { unsigned u[4]; bf16x8 v; };
  U4 p0[4], p1[4];

// one q-set's QK (8 MFMA) + exp2 + pack into its PV A-fragments
#define QKSET(qA, qB, P0, P1)                                                 \
  {                                                                           \
    f32x4 z0 = {}, z1 = {}, z2 = {}, z3 = {};                                 \
    __builtin_amdgcn_s_setprio(1);                                            \
    z0 = mm(k00, qA, z0); z0 = mm(k01, qB, z0);                               \
    z1 = mm(k10, qA, z1); z1 = mm(k11, qB, z1);                               \
    z2 = mm(k20, qA, z2); z2 = mm(k21, qB, z2);                               \
    z3 = mm(k30, qA, z3); z3 = mm(k31, qB, z3);                               \
    __builtin_amdgcn_s_setprio(0);                                            \
    P0.u[0] = cvtpk(ex2(z0[0]), ex2(z0[1]));                                  \
    P0.u[1] = cvtpk(ex2(z0[2]), ex2(z0[3]));                                  \
    P0.u[2] = cvtpk(ex2(z1[0]), ex2(z1[1]));                                  \
    P0.u[3] = cvtpk(ex2(z1[2]), ex2(z1[3]));                                  \
    P1.u[0] = cvtpk(ex2(z2[0]), ex2(z2[1]));                                  \
    P1.u[1] = cvtpk(ex2(z2[2]), ex2(z2[3]));                                  \
    P1.u[2] = cvtpk(ex2(z3[0]), ex2(z3[1]));                                  \
    P1.u[3] = cvtpk(ex2(z3[2]), ex2(z3[3]));                                  \
  }

  for (int it = 0; it < nIt; it++) {
    int cur = it & 1;
    __syncthreads();   // vmcnt(0) drain: K(it)+V(it) ready; prior reads done
    if (it + 1 < nIt) {
      int nb = cur ^ 1;
      GLD16(kp + ssw_k1,          &Kl[nb][(w * 16)     * 64]);
      GLD16(kp + 8 * DH + ssw_k2, &Kl[nb][(w * 16 + 8) * 64]);
      GLD16(vp,                   &Vl[nb][(w * 16)     * 64]);
      GLD16(vp + 8 * NSEQ,        &Vl[nb][(w * 16 + 8) * 64]);
      kp += 64 * DH; vp += 64;
    }

    // K fragments from LDS (permuted rows; 2-way bank aliasing = free)
    const unsigned short* Kb = &Kl[cur][0];
    bf16x8 k00 = ldb(&Kb[(krow0)      * 64 + swk0]);
    bf16x8 k01 = ldb(&Kb[(krow0)      * 64 + swk1]);
    bf16x8 k10 = ldb(&Kb[(krow0 + 4)  * 64 + swk0]);
    bf16x8 k11 = ldb(&Kb[(krow0 + 4)  * 64 + swk1]);
    bf16x8 k20 = ldb(&Kb[(krow0 + 32) * 64 + swk0]);
    bf16x8 k21 = ldb(&Kb[(krow0 + 32) * 64 + swk1]);
    bf16x8 k30 = ldb(&Kb[(krow0 + 36) * 64 + swk0]);
    bf16x8 k31 = ldb(&Kb[(krow0 + 36) * 64 + swk1]);

    // ---- QK in two 2-set clusters (caps live z temps at 32 VGPR) ----
    QKSET(qa[0], qb[0], p0[0], p1[0]);
    QKSET(qa[1], qb[1], p0[1], p1[1]);
    QKSET(qa[2], qb[2], p0[2], p1[2]);
    QKSET(qa[3], qb[3], p0[3], p1[3]);

    // ---- PV: V fragments shared across all 4 q-sets ----
#pragma unroll
    for (int dt = 0; dt < 4; dt++) {
      bf16x8 v0 = ldb(&Vl[cur][(dt * 16 + c) * 64 + sw0]);
      bf16x8 v1 = ldb(&Vl[cur][(dt * 16 + c) * 64 + sw1]);
      __builtin_amdgcn_s_setprio(1);
#pragma unroll
      for (int ss = 0; ss < 4; ss++) {
        acc[ss][dt] = mm(p0[ss].v, v0, acc[ss][dt]);
        acc[ss][dt] = mm(p1[ss].v, v1, acc[ss][dt]);
      }
      __builtin_amdgcn_s_setprio(0);
    }
    __builtin_amdgcn_s_setprio(1);
#pragma unroll
    for (int ss = 0; ss < 4; ss++) {
      accl[ss] = mm(p0[ss].v, ones, accl[ss]);
      accl[ss] = mm(p1[ss].v, ones, accl[ss]);
    }
    __builtin_amdgcn_s_setprio(0);
  }
#undef QKSET

  size_t rb = ((size_t)(b * NH + h) * S + s) * NSEQ + i0 + w * 64;
#pragma unroll
  for (int ss = 0; ss < 4; ss++) {
    size_t rbs = rb + ss * 16;
    if (c == 0) {
#pragma unroll
      for (int rr = 0; rr < 4; rr++)
        lpart[rbs + quad * 4 + rr] = accl[ss][rr];
    }
#pragma unroll
    for (int rr = 0; rr < 4; rr++)
#pragma unroll
      for (int dt = 0; dt < 4; dt++)
        opart[(rbs + quad * 4 + rr) * 64 + dt * 16 + c] = f2bfr(acc[ss][dt][rr]);
  }
}

// ------ Kernel 3b: merge split-KV partials (plain sums) -> ao bf16 ----------
__global__ __launch_bounds__(256) void k_merge(
    const unsigned short* __restrict__ opart,
    const float* __restrict__ lpart,
    unsigned short* __restrict__ ao, int S) {
  int t = blockIdx.x * 256 + threadIdx.x;     // 131072 threads
  int row = t >> 2;                            // (b*NH+h)*NSEQ + i
  int dseg = (t & 3) * 16;
  int b = row >> 14, rem = row & 16383;
  int h = rem >> 12, i = rem & 4095;

  float l = 0.f;
  float o[16];
#pragma unroll
  for (int j = 0; j < 16; j++) o[j] = 0.f;
  for (int s = 0; s < S; s++) {
    size_t rb = ((size_t)(b * NH + h) * S + s) * NSEQ + i;
    l += lpart[rb];
    const unsigned short* p = opart + rb * 64 + dseg;
    u16x8 v0 = *(const u16x8*)p;
    u16x8 v1 = *(const u16x8*)(p + 8);
#pragma unroll
    for (int j = 0; j < 8; j++) {
      o[j]     += bf2f(v0[j]);
      o[8 + j] += bf2f(v1[j]);
    }
  }
  float inv = 1.f / l;
  unsigned short* dst = ao + ((size_t)b * NSEQ + i) * INNER + h * 64 + dseg;
  uint4 pk0 = { pack2(o[0] * inv, o[1] * inv),  pack2(o[2] * inv, o[3] * inv),
                pack2(o[4] * inv, o[5] * inv),  pack2(o[6] * inv, o[7] * inv) };
  uint4 pk1 = { pack2(o[8] * inv, o[9] * inv),  pack2(o[10] * inv, o[11] * inv),
                pack2(o[12] * inv, o[13] * inv),pack2(o[14] * inv, o[15] * inv) };
  *(uint4*)dst = pk0;
  *(uint4*)(dst + 8) = pk1;
}

// ------ Kernel 4: out-proj + residual, BK=128 (3 barriers total) ------------
__global__ __launch_bounds__(256) void k_out(const unsigned short* __restrict__ wob,
                                             const unsigned short* __restrict__ ao,
                                             const float* __restrict__ x,
                                             float* __restrict__ out) {
  int n0 = blockIdx.x * 64;
  int o0 = blockIdx.y * 64;
  int b  = blockIdx.z;
  __shared__ unsigned short Al[64 * 128];
  __shared__ unsigned short Bl[64 * 128];
  int t = threadIdx.x;
  int lane = t & 63, w = t >> 6;
  int c = lane & 15, quad = lane >> 4;
  int wm = w >> 1, wn = w & 1;
  f32x4 acc[2][2] = {};
  int lr = lane >> 4;
  int lchk = lane & 15;
  const unsigned short* apg = wob + (size_t)o0 * INNER;
  const unsigned short* bpg = ao + ((size_t)b * NSEQ + n0) * INNER;
  for (int kt = 0; kt < 2; kt++) {
    if (kt) __syncthreads();
#pragma unroll
    for (int q = 0; q < 4; q++) {
      int r = w * 16 + q * 4 + lr;
      int srcoff = r * INNER + kt * 128 + ((lchk ^ (r & 7)) * 8);
      GLD16(apg + srcoff, Al + (size_t)(w * 16 + q * 4) * 128);
      GLD16(bpg + srcoff, Bl + (size_t)(w * 16 + q * 4) * 128);
    }
    __syncthreads();
#pragma unroll
    for (int ks = 0; ks < 4; ks++) {
      int ra0 = wm * 32 + c, ra1 = ra0 + 16;
      int rb0 = wn * 32 + c, rb1 = rb0 + 16;
      bf16x8 a0 = ldb(&Al[ra0 * 128 + (((ks * 4 + quad) ^ (ra0 & 7)) * 8)]);
      bf16x8 a1 = ldb(&Al[ra1 * 128 + (((ks * 4 + quad) ^ (ra1 & 7)) * 8)]);
      bf16x8 b0 = ldb(&Bl[rb0 * 128 + (((ks * 4 + quad) ^ (rb0 & 7)) * 8)]);
      bf16x8 b1 = ldb(&Bl[rb1 * 128 + (((ks * 4 + quad) ^ (rb1 & 7)) * 8)]);
      acc[0][0] = mm(a0, b0, acc[0][0]);
      acc[0][1] = mm(a0, b1, acc[0][1]);
      acc[1][0] = mm(a1, b0, acc[1][0]);
      acc[1][1] = mm(a1, b1, acc[1][1]);
    }
  }
#pragma unroll
  for (int i = 0; i < 2; i++)
#pragma unroll
    for (int j = 0; j < 2; j++)
#pragma unroll
      for (int rr = 0; rr < 4; rr++) {
        int o = o0 + wm * 32 + i * 16 + quad * 4 + rr;
        int n = n0 + wn * 32 + j * 16 + c;
        size_t idx = ((size_t)b * CCH + o) * NSEQ + n;
        out[idx] = acc[i][j][rr] + x[idx];
      }
}

extern "C" void kernel_launch(void* const* d_in, const int* in_sizes, int n_in,
                              void* d_out, int out_size, void* d_ws, size_t ws_size,
                              hipStream_t stream) {
  const float* x     = (const float*)d_in[0];
  const float* gamma = (const float*)d_in[1];
  const float* wq    = (const float*)d_in[2];
  const float* wo    = (const float*)d_in[3];
  float* out = (float*)d_out;

  const size_t MB = 1u << 20;
  char* ws = (char*)d_ws;
  // ws layout:
  unsigned short* ao  = (unsigned short*)ws;                   // [0,4)  bf16 [B][N][256]
  unsigned short* xn  = (unsigned short*)(ws + 4 * MB);        // [4,8)  bf16 [B][N][256]
  unsigned short* qkv = (unsigned short*)(ws + 8 * MB);        // [8,20) bf16 [B][768][N] (v region used)
  unsigned short* wqb = (unsigned short*)(ws + 20 * MB);       // 384 KB
  unsigned short* wob = (unsigned short*)(ws + 20 * MB + 512 * 1024); // 128 KB
  unsigned short* qt  = (unsigned short*)(ws + 21 * MB);       // [21,25) bf16 [B][H][N][D]
  unsigned short* ktb = (unsigned short*)(ws + 25 * MB);       // [25,29) bf16 [B][H][N][D]
  unsigned short* opart = (unsigned short*)(ws + 29 * MB);     // S*B*H*N*64 bf16
  int S;
  if (ws_size >= 48 * MB) S = 4;
  else if (ws_size >= 40 * MB) S = 2;
  else S = 1;
  size_t opart_bytes = (size_t)S * BATCH * NH * NSEQ * DH * 2;
  float* lpart = (float*)(ws + 29 * MB + opart_bytes);
  int kvlen = NSEQ / S;

  k_lncvt<<<dim3(512),          256, 0, stream>>>(x, gamma, xn, wq, wo, wqb, wob);
  k_qkv  <<<dim3(64, 12, 2),    256, 0, stream>>>(wqb, xn, qkv, qt, ktb);
  k_attn <<<dim3(16, 4, 2 * S), 256, 0, stream>>>(qt, ktb, qkv, opart,
                                                  lpart, S, kvlen);
  k_merge<<<dim3(512),          256, 0, stream>>>(opart, lpart, ao, S);
  k_out  <<<dim3(64, 4, 2),     256, 0, stream>>>(wob, ao, x, out);
}